// Round 2
// baseline (6958.910 us; speedup 1.0000x reference)
//
#include <hip/hip_runtime.h>
#include <cstddef>
#include <cstdint>

// ---------------------------------------------------------------------------
// GRU sequence model (flax GRUCell, gate_fn=silu, activation=tanh)
// T=512, B=128, F_IN=1030, H=512
//   xg = x @ Wi + bi                (parallel GEMM, bf16 MFMA, per 64-t chunk)
//   recurrence: persistent kernel, 32 blocks x 512 thr, Wh in VGPRs,
//               h communicated as bf16 via global double-buffer,
//               device-scope flag barrier per step.
// Output: [carry (B*H) | ys (T*B*H)] fp32
// ---------------------------------------------------------------------------

#define T_STEPS 512
#define BATCH   128
#define F_IN    1030
#define KPAD    1056          // 33 * 32
#define H       512
#define G3      1536          // 3*H
#define TCHUNK  64
#define MCHUNK  (TCHUNK * BATCH)   // 8192 rows per chunk
#define NBLK    32                 // persistent grid size

using f32x4  = __attribute__((ext_vector_type(4)))  float;
using bf16x8 = __attribute__((ext_vector_type(8)))  short;
using u16x8  = __attribute__((ext_vector_type(8)))  unsigned short;
using u16x4  = __attribute__((ext_vector_type(4)))  unsigned short;

__device__ __forceinline__ unsigned short f2bf(float f) {
    unsigned int u = __builtin_bit_cast(unsigned int, f);
    u = (u + 0x7FFFu + ((u >> 16) & 1u)) >> 16;   // round-to-nearest-even
    return (unsigned short)u;
}
__device__ __forceinline__ float bf2f(unsigned short s) {
    unsigned int u = ((unsigned int)s) << 16;
    return __builtin_bit_cast(float, u);
}

// ---------------------------------------------------------------------------
// Wi [F_IN][G3] fp32  ->  wiT [G3][KPAD] bf16 (transposed, zero-padded K)
// ---------------------------------------------------------------------------
__global__ __launch_bounds__(256) void transpose_wi(const float* __restrict__ Wi,
                                                    unsigned short* __restrict__ wiT) {
    __shared__ float t_lds[32][33];
    const int kx = blockIdx.x, gy = blockIdx.y;
    const int tx = threadIdx.x, ty = threadIdx.y;
#pragma unroll
    for (int r = 0; r < 4; ++r) {
        int k = kx * 32 + ty + r * 8;
        int g = gy * 32 + tx;
        t_lds[ty + r * 8][tx] = (k < F_IN) ? Wi[(size_t)k * G3 + g] : 0.f;
    }
    __syncthreads();
#pragma unroll
    for (int r = 0; r < 4; ++r) {
        int g = gy * 32 + ty + r * 8;
        int k = kx * 32 + tx;
        wiT[(size_t)g * KPAD + k] = f2bf(t_lds[tx][ty + r * 8]);
    }
}

// ---------------------------------------------------------------------------
// Wh_rz [H][2H], Wh_n [H][H] fp32 -> whT [G3][H] bf16 column-major
// ---------------------------------------------------------------------------
__global__ __launch_bounds__(256) void transpose_wh(const float* __restrict__ Whrz,
                                                    const float* __restrict__ Whn,
                                                    unsigned short* __restrict__ whT) {
    __shared__ float t_lds[32][33];
    const int kx = blockIdx.x, cy = blockIdx.y;
    const int tx = threadIdx.x, ty = threadIdx.y;
#pragma unroll
    for (int r = 0; r < 4; ++r) {
        int k = kx * 32 + ty + r * 8;
        int c = cy * 32 + tx;
        float v = (c < 1024) ? Whrz[(size_t)k * 1024 + c]
                             : Whn[(size_t)k * H + (c - 1024)];
        t_lds[ty + r * 8][tx] = v;
    }
    __syncthreads();
#pragma unroll
    for (int r = 0; r < 4; ++r) {
        int c = cy * 32 + ty + r * 8;
        int k = kx * 32 + tx;
        whT[(size_t)c * H + k] = f2bf(t_lds[tx][ty + r * 8]);
    }
}

// ---------------------------------------------------------------------------
// init: h0 fp32 -> h_bf[0] bf16, zero barrier counter
// ---------------------------------------------------------------------------
__global__ __launch_bounds__(256) void init_hbf(const float* __restrict__ h0,
                                                unsigned short* __restrict__ h_bf,
                                                unsigned int* __restrict__ cnt) {
    int i = blockIdx.x * 256 + threadIdx.x;
    if (i == 0) *cnt = 0u;
    if (i < BATCH * H) h_bf[i] = f2bf(h0[i]);
}

// ---------------------------------------------------------------------------
// xg chunk GEMM: [MCHUNK][F_IN] fp32 @ wiT -> xg [MCHUNK][G3] bf16 (+bi)
// 64x64 tile, BK=32, 256 thr. grid (G3/64=24, MCHUNK/64=128)
// ---------------------------------------------------------------------------
__global__ __launch_bounds__(256) void gemm_xg(const float* __restrict__ x,
                                               const unsigned short* __restrict__ wiT,
                                               const float* __restrict__ bi,
                                               unsigned short* __restrict__ xg) {
    __shared__ unsigned short a_lds[64][40];
    __shared__ unsigned short b_lds[64][40];
    const int tid = threadIdx.x;
    const int n0 = blockIdx.x * 64;
    const int m0 = blockIdx.y * 64;
    const int l = tid & 63, w = tid >> 6;
    const int wr = w >> 1, wc = w & 1;
    const int si = tid >> 2;
    const int sk = (tid & 3) * 8;

    f32x4 acc[2][2] = {};

    for (int kt = 0; kt < 33; ++kt) {
        if (kt) __syncthreads();
        {
            const int kb = kt * 32 + sk;
            const float* src = x + (size_t)(m0 + si) * F_IN + kb;
            u16x8 v;
#pragma unroll
            for (int e = 0; e < 8; ++e)
                v[e] = (kb + e < F_IN) ? f2bf(src[e]) : (unsigned short)0;
            *(u16x8*)&a_lds[si][sk] = v;
            *(u16x8*)&b_lds[si][sk] =
                *(const u16x8*)(wiT + (size_t)(n0 + si) * KPAD + kt * 32 + sk);
        }
        __syncthreads();
        const int ka = (l >> 4) * 8;
        bf16x8 a0 = *(const bf16x8*)&a_lds[wr * 32 + (l & 15)][ka];
        bf16x8 a1 = *(const bf16x8*)&a_lds[wr * 32 + 16 + (l & 15)][ka];
        bf16x8 b0 = *(const bf16x8*)&b_lds[wc * 32 + (l & 15)][ka];
        bf16x8 b1 = *(const bf16x8*)&b_lds[wc * 32 + 16 + (l & 15)][ka];
        acc[0][0] = __builtin_amdgcn_mfma_f32_16x16x32_bf16(a0, b0, acc[0][0], 0, 0, 0);
        acc[0][1] = __builtin_amdgcn_mfma_f32_16x16x32_bf16(a0, b1, acc[0][1], 0, 0, 0);
        acc[1][0] = __builtin_amdgcn_mfma_f32_16x16x32_bf16(a1, b0, acc[1][0], 0, 0, 0);
        acc[1][1] = __builtin_amdgcn_mfma_f32_16x16x32_bf16(a1, b1, acc[1][1], 0, 0, 0);
    }

#pragma unroll
    for (int n = 0; n < 2; ++n) {
        const int col = n0 + wc * 32 + n * 16 + (l & 15);
        const float bv = bi[col];
#pragma unroll
        for (int m = 0; m < 2; ++m) {
#pragma unroll
            for (int q = 0; q < 4; ++q) {
                const int row = m0 + wr * 32 + m * 16 + (l >> 4) * 4 + q;
                xg[(size_t)row * G3 + col] = f2bf(acc[m][n][q] + bv);
            }
        }
    }
}

// ---------------------------------------------------------------------------
// Persistent GRU recurrence over one 64-step chunk.
// grid (4,8) = 32 blocks (j-tile 128 cols x b-tile 16 rows), 512 thr (8 waves).
// Wave w owns cols j0 + w*16 + (l&15); Wh fragments held in VGPRs (48 bf16x8).
// h: bf16 double-buffer in ws (global); fp32 h kept in regs for z*h term.
// Per-step device-scope barrier: monotonic counter in ws.
// ---------------------------------------------------------------------------
__global__ __launch_bounds__(512, 2) void gru_persist(
    const unsigned short* __restrict__ xg,    // chunk [TCHUNK*B][G3]
    const unsigned short* __restrict__ whT,   // [G3][H]
    const float* __restrict__ bhn,            // [H]
    const float* __restrict__ h_init_f,       // fp32 h at t0 (h0 or ys[t0-1])
    unsigned short* __restrict__ h_bf,        // [2][B][H] bf16
    float* __restrict__ ys,                   // [T][B][H] fp32 (full)
    float* __restrict__ carry,                // [B][H] fp32
    unsigned int* __restrict__ cnt,
    int t0, int nsteps, unsigned int arrive_base)
{
    __shared__ unsigned short h_lds[16][520];   // [b_local][k], stride 520 (2-way ok)
    const int tid = threadIdx.x;
    const int l = tid & 63, w = tid >> 6;       // lane, wave 0..7
    const int j0 = blockIdx.x * 128;
    const int b0 = blockIdx.y * 16;
    const int jc = j0 + w * 16 + (l & 15);      // this thread's output col
    const int br = (l >> 4) * 4;                // base row in b-tile (q adds 0..3)

    // ---- loop-invariant: Wh B-fragments in VGPRs (3 gates x 16 k-steps) ----
    bf16x8 wb[3][16];
#pragma unroll
    for (int g = 0; g < 3; ++g)
#pragma unroll
        for (int kt = 0; kt < 16; ++kt)
            wb[g][kt] = *(const bf16x8*)(whT + ((size_t)(g * H + jc)) * H
                                             + kt * 32 + (l >> 4) * 8);
    const float bnv = bhn[jc];

    // fp32 h at own output coords
    float hreg[4];
#pragma unroll
    for (int q = 0; q < 4; ++q)
        hreg[q] = h_init_f[(size_t)(b0 + br + q) * H + jc];

    for (int s = 0; s < nsteps; ++s) {
        const int t = t0 + s;
        // ---- stage h_t (bf16) rows b0..b0+15 into LDS ----
        const unsigned short* hsrc = h_bf + ((size_t)(t & 1)) * BATCH * H
                                          + (size_t)b0 * H;
        {
            const int row = tid >> 5;            // 0..15
            const int k0  = (tid & 31) * 16;     // 0..496
            *(u16x8*)&h_lds[row][k0]     = *(const u16x8*)(hsrc + (size_t)row * H + k0);
            *(u16x8*)&h_lds[row][k0 + 8] = *(const u16x8*)(hsrc + (size_t)row * H + k0 + 8);
        }
        // ---- prefetch xg gate inputs (independent of h) ----
        float xr[4], xz[4], xn[4];
#pragma unroll
        for (int q = 0; q < 4; ++q) {
            const size_t rb = ((size_t)s * BATCH + b0 + br + q) * G3;
            xr[q] = bf2f(xg[rb + jc]);
            xz[q] = bf2f(xg[rb + H + jc]);
            xn[q] = bf2f(xg[rb + 2 * H + jc]);
        }
        __syncthreads();
        // ---- MFMA: [16 rows x 16 cols x 3 gates], K=512 ----
        f32x4 a0 = {}, a1 = {}, a2 = {};
#pragma unroll
        for (int kt = 0; kt < 16; ++kt) {
            bf16x8 a = *(const bf16x8*)&h_lds[l & 15][kt * 32 + (l >> 4) * 8];
            a0 = __builtin_amdgcn_mfma_f32_16x16x32_bf16(a, wb[0][kt], a0, 0, 0, 0);
            a1 = __builtin_amdgcn_mfma_f32_16x16x32_bf16(a, wb[1][kt], a1, 0, 0, 0);
            a2 = __builtin_amdgcn_mfma_f32_16x16x32_bf16(a, wb[2][kt], a2, 0, 0, 0);
        }
        // ---- gates + state update ----
        float* yst = ys + (size_t)t * BATCH * H;
        unsigned short* hdst = h_bf + ((size_t)((t + 1) & 1)) * BATCH * H;
#pragma unroll
        for (int q = 0; q < 4; ++q) {
            const float pr = xr[q] + a0[q];
            const float pz = xz[q] + a1[q];
            const float r = pr / (1.f + __expf(-pr));    // silu
            const float z = pz / (1.f + __expf(-pz));
            const float n = tanhf(xn[q] + r * (a2[q] + bnv));
            const float ho = (1.f - z) * n + z * hreg[q];
            hreg[q] = ho;
            const size_t o = (size_t)(b0 + br + q) * H + jc;
            yst[o] = ho;
            hdst[o] = f2bf(ho);
            if (t == T_STEPS - 1) carry[o] = ho;
        }
        // ---- device-scope barrier (skip after last step of this launch) ----
        if (s + 1 < nsteps) {
            __syncthreads();                       // drains vmcnt per wave
            if (tid == 0) {
                __hip_atomic_fetch_add(cnt, 1u, __ATOMIC_ACQ_REL,
                                       __HIP_MEMORY_SCOPE_AGENT);  // rel: L2 wb
                const unsigned tgt = arrive_base + (unsigned)(NBLK * (s + 1));
                while (__hip_atomic_load(cnt, __ATOMIC_RELAXED,
                                         __HIP_MEMORY_SCOPE_AGENT) < tgt)
                    __builtin_amdgcn_s_sleep(1);
            }
            __syncthreads();
            __builtin_amdgcn_fence(__ATOMIC_ACQUIRE, "agent");  // per-wave inv
        }
    }
}

// ---------------------------------------------------------------------------
extern "C" void kernel_launch(void* const* d_in, const int* in_sizes, int n_in,
                              void* d_out, int out_size, void* d_ws, size_t ws_size,
                              hipStream_t stream) {
    const float* h0   = (const float*)d_in[0];
    const float* x    = (const float*)d_in[1];
    const float* Wi   = (const float*)d_in[2];
    const float* bi   = (const float*)d_in[3];
    const float* Whrz = (const float*)d_in[4];
    const float* Whn  = (const float*)d_in[5];
    const float* bhn  = (const float*)d_in[6];

    float* carry = (float*)d_out;                       // [B][H]
    float* ys    = (float*)d_out + (size_t)BATCH * H;   // [T][B][H]

    // ws layout: wiT [G3][KPAD] | whT [G3][H] | xg [MCHUNK][G3] | h_bf [2][B][H] | cnt
    unsigned short* wiT  = (unsigned short*)d_ws;
    unsigned short* whT  = wiT + (size_t)G3 * KPAD;
    unsigned short* xg   = whT + (size_t)G3 * H;
    unsigned short* h_bf = xg + (size_t)MCHUNK * G3;
    unsigned int*   cnt  = (unsigned int*)(h_bf + (size_t)2 * BATCH * H);

    transpose_wi<<<dim3(KPAD / 32, G3 / 32), dim3(32, 8), 0, stream>>>(Wi, wiT);
    transpose_wh<<<dim3(H / 32, G3 / 32), dim3(32, 8), 0, stream>>>(Whrz, Whn, whT);
    init_hbf<<<dim3((BATCH * H) / 256), 256, 0, stream>>>(h0, h_bf, cnt);

    for (int c = 0; c < T_STEPS / TCHUNK; ++c) {
        gemm_xg<<<dim3(G3 / 64, MCHUNK / 64), 256, 0, stream>>>(
            x + (size_t)c * MCHUNK * F_IN, wiT, bi, xg);
        const int t0 = c * TCHUNK;
        const float* hinit = (c == 0) ? h0 : ys + (size_t)(t0 - 1) * BATCH * H;
        gru_persist<<<dim3(4, 8), 512, 0, stream>>>(
            xg, whT, bhn, hinit, h_bf, ys, carry, cnt,
            t0, TCHUNK, (unsigned)(c * (TCHUNK - 1) * NBLK));
    }
}

// Round 3
// 3479.441 us; speedup vs baseline: 2.0000x; 2.0000x over previous
//
#include <hip/hip_runtime.h>
#include <cstddef>
#include <cstdint>

// ---------------------------------------------------------------------------
// GRU sequence model (flax GRUCell, gate_fn=silu, activation=tanh)
// T=512, B=128, F_IN=1030, H=512
//   xg = x @ Wi + bi     (128^2-tile bf16 MFMA GEMM, cvt_pk A-staging)
//   recurrence: persistent kernel, 8 independent groups (16 batch rows) x
//     4 j-blocks; Wh pinned in VGPRs; h via agent-coherent atomics;
//     per-group relaxed flag barrier (NO L2 invalidate/writeback).
// Output: [carry (B*H) | ys (T*B*H)] fp32
// ---------------------------------------------------------------------------

#define T_STEPS 512
#define BATCH   128
#define F_IN    1030
#define KPAD    1056          // 33 * 32
#define H       512
#define G3      1536          // 3*H
#define TCHUNK  64
#define MCHUNK  (TCHUNK * BATCH)   // 8192 rows per chunk
#define GRPBLK  4                  // j-blocks per batch group

using f32x4  = __attribute__((ext_vector_type(4)))  float;
using bf16x8 = __attribute__((ext_vector_type(8)))  short;
using u16x8  = __attribute__((ext_vector_type(8)))  unsigned short;

__device__ __forceinline__ unsigned short f2bf(float f) {
    unsigned int u = __builtin_bit_cast(unsigned int, f);
    u = (u + 0x7FFFu + ((u >> 16) & 1u)) >> 16;   // RNE
    return (unsigned short)u;
}
__device__ __forceinline__ float bf2f(unsigned short s) {
    unsigned int u = ((unsigned int)s) << 16;
    return __builtin_bit_cast(float, u);
}
__device__ __forceinline__ unsigned int cvt2bf(float lo, float hi) {
    unsigned int r;
    asm("v_cvt_pk_bf16_f32 %0, %1, %2" : "=v"(r) : "v"(lo), "v"(hi));
    return r;
}

// ---------------------------------------------------------------------------
// Wi [F_IN][G3] fp32  ->  wiT [G3][KPAD] bf16 (transposed, zero-padded K)
// ---------------------------------------------------------------------------
__global__ __launch_bounds__(256) void transpose_wi(const float* __restrict__ Wi,
                                                    unsigned short* __restrict__ wiT) {
    __shared__ float t_lds[32][33];
    const int kx = blockIdx.x, gy = blockIdx.y;
    const int tx = threadIdx.x, ty = threadIdx.y;
#pragma unroll
    for (int r = 0; r < 4; ++r) {
        int k = kx * 32 + ty + r * 8;
        int g = gy * 32 + tx;
        t_lds[ty + r * 8][tx] = (k < F_IN) ? Wi[(size_t)k * G3 + g] : 0.f;
    }
    __syncthreads();
#pragma unroll
    for (int r = 0; r < 4; ++r) {
        int g = gy * 32 + ty + r * 8;
        int k = kx * 32 + tx;
        wiT[(size_t)g * KPAD + k] = f2bf(t_lds[tx][ty + r * 8]);
    }
}

// ---------------------------------------------------------------------------
// Wh_rz [H][2H], Wh_n [H][H] fp32 -> whT [G3][H] bf16 column-major
// ---------------------------------------------------------------------------
__global__ __launch_bounds__(256) void transpose_wh(const float* __restrict__ Whrz,
                                                    const float* __restrict__ Whn,
                                                    unsigned short* __restrict__ whT) {
    __shared__ float t_lds[32][33];
    const int kx = blockIdx.x, cy = blockIdx.y;
    const int tx = threadIdx.x, ty = threadIdx.y;
#pragma unroll
    for (int r = 0; r < 4; ++r) {
        int k = kx * 32 + ty + r * 8;
        int c = cy * 32 + tx;
        float v = (c < 1024) ? Whrz[(size_t)k * 1024 + c]
                             : Whn[(size_t)k * H + (c - 1024)];
        t_lds[ty + r * 8][tx] = v;
    }
    __syncthreads();
#pragma unroll
    for (int r = 0; r < 4; ++r) {
        int c = cy * 32 + ty + r * 8;
        int k = kx * 32 + tx;
        whT[(size_t)c * H + k] = f2bf(t_lds[tx][ty + r * 8]);
    }
}

// ---------------------------------------------------------------------------
// init: h0 fp32 -> h_bf[0] bf16; zero group counters
// ---------------------------------------------------------------------------
__global__ __launch_bounds__(256) void init_hbf(const float* __restrict__ h0,
                                                unsigned short* __restrict__ h_bf,
                                                unsigned int* __restrict__ cnts) {
    int i = blockIdx.x * 256 + threadIdx.x;
    if (blockIdx.x == 0) { cnts[threadIdx.x] = 0u; cnts[threadIdx.x + 256] = 0u; }
    if (i < BATCH * H) h_bf[i] = f2bf(h0[i]);
}

// ---------------------------------------------------------------------------
// xg chunk GEMM: [MCHUNK][F_IN] fp32 @ wiT -> xg [MCHUNK][G3] bf16 (+bi)
// 128x128 tile, BK=32, 256 thr (2x2 waves, 4x4 frags each).
// grid (G3/128=12, MCHUNK/128=64)
// ---------------------------------------------------------------------------
__global__ __launch_bounds__(256) void gemm_xg(const float* __restrict__ x,
                                               const unsigned short* __restrict__ wiT,
                                               const float* __restrict__ bi,
                                               unsigned short* __restrict__ xg) {
    __shared__ unsigned short a_lds[128][40];   // pitch 40 u16 = 80B (5 slots)
    __shared__ unsigned short b_lds[128][40];
    const int tid = threadIdx.x;
    const int n0 = blockIdx.x * 128;
    const int m0 = blockIdx.y * 128;
    const int l = tid & 63, w = tid >> 6;
    const int wr = w >> 1, wc = w & 1;          // 2x2 over 64x64 quadrants
    const int sr = tid >> 1;                    // staging row/col 0..127
    const int sk = (tid & 1) * 16;              // k sub-slice 0 or 16

    f32x4 acc[4][4] = {};

    for (int kt = 0; kt < 33; ++kt) {
        if (kt) __syncthreads();
        // ---- stage A: fp32 -> bf16 (float2 loads, cvt_pk) ----
        {
            const int kb = kt * 32 + sk;
            const float* srcp = x + (size_t)(m0 + sr) * F_IN + kb;
            float2 f2v[8];
#pragma unroll
            for (int i = 0; i < 8; ++i) {
                int k = kb + 2 * i;
                if (k < F_IN) f2v[i] = *(const float2*)(srcp + 2 * i);
                else          f2v[i] = make_float2(0.f, 0.f);
            }
            uint4 p0, p1;
            p0.x = cvt2bf(f2v[0].x, f2v[0].y); p0.y = cvt2bf(f2v[1].x, f2v[1].y);
            p0.z = cvt2bf(f2v[2].x, f2v[2].y); p0.w = cvt2bf(f2v[3].x, f2v[3].y);
            p1.x = cvt2bf(f2v[4].x, f2v[4].y); p1.y = cvt2bf(f2v[5].x, f2v[5].y);
            p1.z = cvt2bf(f2v[6].x, f2v[6].y); p1.w = cvt2bf(f2v[7].x, f2v[7].y);
            *(uint4*)&a_lds[sr][sk]     = p0;
            *(uint4*)&a_lds[sr][sk + 8] = p1;
            // ---- stage B (bf16 passthrough) ----
            const unsigned short* bsrc = wiT + (size_t)(n0 + sr) * KPAD + kb;
            *(uint4*)&b_lds[sr][sk]     = *(const uint4*)bsrc;
            *(uint4*)&b_lds[sr][sk + 8] = *(const uint4*)(bsrc + 8);
        }
        __syncthreads();
        const int ka = (l >> 4) * 8;
        bf16x8 af[4], bfr[4];
#pragma unroll
        for (int mi = 0; mi < 4; ++mi)
            af[mi] = *(const bf16x8*)&a_lds[wr * 64 + mi * 16 + (l & 15)][ka];
#pragma unroll
        for (int nj = 0; nj < 4; ++nj)
            bfr[nj] = *(const bf16x8*)&b_lds[wc * 64 + nj * 16 + (l & 15)][ka];
#pragma unroll
        for (int mi = 0; mi < 4; ++mi)
#pragma unroll
            for (int nj = 0; nj < 4; ++nj)
                acc[mi][nj] = __builtin_amdgcn_mfma_f32_16x16x32_bf16(
                    af[mi], bfr[nj], acc[mi][nj], 0, 0, 0);
    }

    // epilogue: D col = l&15, row = (l>>4)*4 + q
#pragma unroll
    for (int nj = 0; nj < 4; ++nj) {
        const int col = n0 + wc * 64 + nj * 16 + (l & 15);
        const float bv = bi[col];
#pragma unroll
        for (int mi = 0; mi < 4; ++mi) {
#pragma unroll
            for (int q = 0; q < 4; ++q) {
                const int row = m0 + wr * 64 + mi * 16 + (l >> 4) * 4 + q;
                xg[(size_t)row * G3 + col] = f2bf(acc[mi][nj][q] + bv);
            }
        }
    }
}

// ---------------------------------------------------------------------------
// Persistent GRU recurrence over one 64-step chunk.
// grid (4,8): 8 independent batch groups x 4 j-blocks. 512 thr (8 waves).
// Wh B-fragments pinned in VGPRs; h via agent-coherent atomics (u32);
// per-group relaxed counter barrier (no fences -> L2 stays hot for xg/whT).
// ---------------------------------------------------------------------------
__global__ __launch_bounds__(512, 2) void gru_persist(
    const unsigned short* __restrict__ xg,    // chunk [TCHUNK*B][G3]
    const unsigned short* __restrict__ whT,   // [G3][H]
    const float* __restrict__ bhn,            // [H]
    const float* __restrict__ h_init_f,       // fp32 h at t0
    unsigned short* __restrict__ h_bf,        // [2][B][H] bf16
    float* __restrict__ ys,                   // [T][B][H] fp32
    float* __restrict__ carry,                // [B][H] fp32
    unsigned int* __restrict__ cnts,
    int t0, int nsteps, unsigned int base)
{
    __shared__ unsigned short h_lds[16][520];   // pitch 520 u16 (65 slots, cf-free)
    const int tid = threadIdx.x;
    const int l = tid & 63, w = tid >> 6;
    const int j0 = blockIdx.x * 128;
    const int by = blockIdx.y;
    const int b0 = by * 16;
    const int jc = j0 + w * 16 + (l & 15);
    const int br = (l >> 4) * 4;
    unsigned int* cnt = cnts + by * 32;         // 128B apart per group

    // ---- load Wh fragments once, PIN in VGPRs ----
    bf16x8 wb[3][16];
#pragma unroll
    for (int g = 0; g < 3; ++g)
#pragma unroll
        for (int kt = 0; kt < 16; ++kt)
            wb[g][kt] = *(const bf16x8*)(whT + ((size_t)(g * H + jc)) * H
                                             + kt * 32 + (l >> 4) * 8);
#pragma unroll
    for (int g = 0; g < 3; ++g)
#pragma unroll
        for (int kt = 0; kt < 16; ++kt)
            asm volatile("" : "+v"(wb[g][kt]));
    const float bnv = bhn[jc];

    float hreg[4];
#pragma unroll
    for (int q = 0; q < 4; ++q)
        hreg[q] = h_init_f[(size_t)(b0 + br + q) * H + jc];

    // xg raw prefetch for s=0 (u16 regs, converted at use)
    unsigned short pxr[4], pxz[4], pxn[4];
#pragma unroll
    for (int q = 0; q < 4; ++q) {
        const size_t rb = ((size_t)(b0 + br + q)) * G3;
        pxr[q] = xg[rb + jc]; pxz[q] = xg[rb + H + jc]; pxn[q] = xg[rb + 2 * H + jc];
    }

    const int hrow = tid >> 5;                  // 0..15
    const int hcol = (tid & 31) * 8;            // u32 col 0..248

    for (int s = 0; s < nsteps; ++s) {
        const int t = t0 + s;
        // ---- coherent h load: 8 u32/thread from h_bf[t&1], group rows ----
        const unsigned int* hsrc = (const unsigned int*)(h_bf
            + ((size_t)(t & 1)) * BATCH * H + (size_t)b0 * H);
        unsigned int hv[8];
#pragma unroll
        for (int i = 0; i < 8; ++i)
            hv[i] = __hip_atomic_load(hsrc + (size_t)hrow * 256 + hcol + i,
                                      __ATOMIC_RELAXED, __HIP_MEMORY_SCOPE_AGENT);
        unsigned int* hl = (unsigned int*)&h_lds[0][0];
#pragma unroll
        for (int i = 0; i < 8; ++i)
            hl[hrow * 260 + hcol + i] = hv[i];
        __syncthreads();
        // ---- MFMA: 16 rows x 16 cols x 3 gates, K=512 ----
        f32x4 a0 = {}, a1 = {}, a2 = {};
#pragma unroll
        for (int kt = 0; kt < 16; ++kt) {
            bf16x8 a = *(const bf16x8*)&h_lds[l & 15][kt * 32 + (l >> 4) * 8];
            a0 = __builtin_amdgcn_mfma_f32_16x16x32_bf16(a, wb[0][kt], a0, 0, 0, 0);
            a1 = __builtin_amdgcn_mfma_f32_16x16x32_bf16(a, wb[1][kt], a1, 0, 0, 0);
            a2 = __builtin_amdgcn_mfma_f32_16x16x32_bf16(a, wb[2][kt], a2, 0, 0, 0);
        }
        // ---- gates + state update ----
        float* yst = ys + (size_t)t * BATCH * H;
        unsigned int* hdst = (unsigned int*)(h_bf + ((size_t)((t + 1) & 1)) * BATCH * H);
        unsigned short hb[4];
#pragma unroll
        for (int q = 0; q < 4; ++q) {
            const float pr = bf2f(pxr[q]) + a0[q];
            const float pz = bf2f(pxz[q]) + a1[q];
            const float r = pr / (1.f + __expf(-pr));
            const float z = pz / (1.f + __expf(-pz));
            const float n = tanhf(bf2f(pxn[q]) + r * (a2[q] + bnv));
            const float ho = (1.f - z) * n + z * hreg[q];
            hreg[q] = ho;
            hb[q] = f2bf(ho);
            const size_t o = (size_t)(b0 + br + q) * H + jc;
            yst[o] = ho;
            if (t == T_STEPS - 1) carry[o] = ho;
        }
        // ---- pack pairs via shfl, even lanes store u32 coherent ----
#pragma unroll
        for (int q = 0; q < 4; ++q) {
            unsigned int other = __shfl_xor((unsigned int)hb[q], 1);
            if ((l & 1) == 0) {
                unsigned int val = (unsigned int)hb[q] | (other << 16);
                const size_t o2 = ((size_t)(b0 + br + q) * H + jc) >> 1;
                __hip_atomic_store(hdst + o2, val, __ATOMIC_RELAXED,
                                   __HIP_MEMORY_SCOPE_AGENT);
            }
        }
        if (s + 1 < nsteps) {
            __syncthreads();   // drains vmcnt in every wave -> h stores visible
            // prefetch next-step xg (raw u16; stays in flight across barrier)
#pragma unroll
            for (int q = 0; q < 4; ++q) {
                const size_t rb = ((size_t)(s + 1) * BATCH + b0 + br + q) * G3;
                pxr[q] = xg[rb + jc]; pxz[q] = xg[rb + H + jc]; pxn[q] = xg[rb + 2 * H + jc];
            }
            if (tid == 0) {
                __hip_atomic_fetch_add(cnt, 1u, __ATOMIC_RELAXED,
                                       __HIP_MEMORY_SCOPE_AGENT);
                const unsigned tgt = base + (unsigned)(GRPBLK * (s + 1));
                while (__hip_atomic_load(cnt, __ATOMIC_RELAXED,
                                         __HIP_MEMORY_SCOPE_AGENT) < tgt)
                    __builtin_amdgcn_s_sleep(1);
            }
            __builtin_amdgcn_sched_barrier(0);
            __builtin_amdgcn_s_barrier();
            __builtin_amdgcn_sched_barrier(0);
        }
    }
}

// ---------------------------------------------------------------------------
extern "C" void kernel_launch(void* const* d_in, const int* in_sizes, int n_in,
                              void* d_out, int out_size, void* d_ws, size_t ws_size,
                              hipStream_t stream) {
    const float* h0   = (const float*)d_in[0];
    const float* x    = (const float*)d_in[1];
    const float* Wi   = (const float*)d_in[2];
    const float* bi   = (const float*)d_in[3];
    const float* Whrz = (const float*)d_in[4];
    const float* Whn  = (const float*)d_in[5];
    const float* bhn  = (const float*)d_in[6];

    float* carry = (float*)d_out;
    float* ys    = (float*)d_out + (size_t)BATCH * H;

    // ws: wiT [G3][KPAD] | whT [G3][H] | xg [MCHUNK][G3] | h_bf [2][B][H] | cnts
    unsigned short* wiT  = (unsigned short*)d_ws;
    unsigned short* whT  = wiT + (size_t)G3 * KPAD;
    unsigned short* xg   = whT + (size_t)G3 * H;
    unsigned short* h_bf = xg + (size_t)MCHUNK * G3;
    unsigned int*   cnts = (unsigned int*)(h_bf + (size_t)2 * BATCH * H);

    transpose_wi<<<dim3(KPAD / 32, G3 / 32), dim3(32, 8), 0, stream>>>(Wi, wiT);
    transpose_wh<<<dim3(H / 32, G3 / 32), dim3(32, 8), 0, stream>>>(Whrz, Whn, whT);
    init_hbf<<<dim3((BATCH * H) / 256), 256, 0, stream>>>(h0, h_bf, cnts);

    for (int c = 0; c < T_STEPS / TCHUNK; ++c) {
        gemm_xg<<<dim3(G3 / 128, MCHUNK / 128), 256, 0, stream>>>(
            x + (size_t)c * MCHUNK * F_IN, wiT, bi, xg);
        const int t0 = c * TCHUNK;
        const float* hinit = (c == 0) ? h0 : ys + (size_t)(t0 - 1) * BATCH * H;
        gru_persist<<<dim3(GRPBLK, 8), 512, 0, stream>>>(
            xg, whT, bhn, hinit, h_bf, ys, carry, cnts,
            t0, TCHUNK, (unsigned)(c * (TCHUNK - 1) * GRPBLK));
    }
}